// Round 11
// baseline (552.270 us; speedup 1.0000x reference)
//
#include <hip/hip_runtime.h>
#include <cmath>
#include <cstdint>

// Problem constants (from reference)
constexpr int B_ = 8, N_ = 1024, M_ = 512, D_ = 128, S_ = 1536, L_ = 6, DFF_ = 512;
constexpr int ROWS = B_ * S_;    // 12288
constexpr int MAXDEG = 64;       // max attention row degree (actual ~4-20)
constexpr int LKEY = 32;         // LDS-cached keys per row
constexpr int RPB  = 16;         // rows per block
constexpr int NBLK = ROWS / RPB; // 768 blocks = 3 per CU (all resident: LDS 47K*3<160K)
constexpr int BPBATCH = S_ / RPB;// 96 blocks per batch (per-batch barrier group)

typedef __bf16 bf16x8 __attribute__((ext_vector_type(8)));
typedef float  f32x4  __attribute__((ext_vector_type(4)));
typedef unsigned short u16x8 __attribute__((ext_vector_type(8)));

__device__ inline unsigned short f2bf(float f) {  // RNE fp32 -> bf16
  unsigned u = __float_as_uint(f);
  u += 0x7fffu + ((u >> 16) & 1u);
  return (unsigned short)(u >> 16);
}
__device__ inline float bf2f(unsigned short u) {
  return __uint_as_float(((unsigned)u) << 16);
}
__device__ inline void ull2f4(unsigned long long u, float* f) {  // 4 bf16 -> fp32
  f[0] = bf2f((unsigned short)(u));
  f[1] = bf2f((unsigned short)(u >> 16));
  f[2] = bf2f((unsigned short)(u >> 32));
  f[3] = bf2f((unsigned short)(u >> 48));
}

// ---------------------------------------------------------------------------
// Adjacency from pcm (one wave per row). exp(-1e9-max) underflows to 0 in
// fp32 => sparse attention over this list == dense masked softmax.
// ---------------------------------------------------------------------------
__global__ void adj_kernel(const int* __restrict__ pcm, int* __restrict__ adj,
                           int* __restrict__ adjcnt) {
  int s = blockIdx.x;
  int lane = threadIdx.x;
  int count = 0;
  for (int base = 0; base < S_; base += 64) {
    int k = base + lane;
    bool allowed;
    if (k == s) allowed = true;
    else if (s < N_ && k >= N_) allowed = pcm[(k - N_) * N_ + s] != 0;
    else if (s >= N_ && k < N_) allowed = pcm[(s - N_) * N_ + k] != 0;
    else allowed = false;
    unsigned long long bal = __ballot(allowed);
    if (allowed) {
      int slot = count + __popcll(bal & ((1ull << lane) - 1ull));
      if (slot < MAXDEG) adj[s * MAXDEG + slot] = k;
    }
    count += __popcll(bal);
  }
  if (lane == 0) adjcnt[s] = count < MAXDEG ? count : MAXDEG;
}

// ---------------------------------------------------------------------------
// x init; also zeroes the 8 per-batch barrier counters (ws poisoned 0xAA).
// ---------------------------------------------------------------------------
__global__ void xinit_kernel(const float* __restrict__ r_t, const int* __restrict__ adj,
                             const int* __restrict__ adjcnt, const float* __restrict__ se,
                             const int* __restrict__ tt, const float* __restrict__ table,
                             float* __restrict__ x, unsigned* __restrict__ barrier_cnt) {
  int bs = blockIdx.x;
  int b = bs / S_, s = bs % S_;
  int d = threadIdx.x;
  if (bs < 8 && d == 0)
    __hip_atomic_store(barrier_cnt + bs * 32, 0u, __ATOMIC_RELAXED, __HIP_MEMORY_SCOPE_AGENT);
  float node;
  if (s < N_) {
    node = fabsf(r_t[b * N_ + s]);
  } else {
    int cnt = adjcnt[s];
    float sum = 0.f;
    for (int j = 0; j < cnt; ++j) {
      int k = adj[s * MAXDEG + j];
      if (k < N_) {
        float r = r_t[b * N_ + k];
        sum += (r < 0.f) ? 1.f : (r > 0.f ? 0.f : 0.5f);
      }
    }
    node = fmodf(sum, 2.0f);
  }
  x[(size_t)bs * D_ + d] = table[tt[b] * D_ + d] * se[s * D_ + d] * node;
}

// ---------------------------------------------------------------------------
// Weight convert: fp32 [K][N] -> bf16 transposed [N][K], per layer packed as
//   [3*128][128] (q,k,v) | [128][128] (o) | [512][128] (w1) | [128][512] (w2)
// ---------------------------------------------------------------------------
constexpr int WSEG_QKV = 3 * D_ * D_;
constexpr int WSEG_O   = D_ * D_;
constexpr int WSEG_1   = D_ * DFF_;
constexpr int WSEG_2   = DFF_ * D_;
constexpr int WLAYER   = WSEG_QKV + WSEG_O + WSEG_1 + WSEG_2;  // 196608

__global__ void wconv_kernel(const float* __restrict__ Wq, const float* __restrict__ Wk,
                             const float* __restrict__ Wv, const float* __restrict__ Wo,
                             const float* __restrict__ W1, const float* __restrict__ W2,
                             unsigned short* __restrict__ out) {
  int idx = blockIdx.x * blockDim.x + threadIdx.x;
  if (idx >= L_ * WLAYER) return;
  int l = idx / WLAYER, r = idx % WLAYER;
  float v;
  if (r < WSEG_QKV) {
    int which = r / (D_ * D_), i = r % (D_ * D_);
    int n = i / D_, kk = i % D_;
    const float* W = which == 0 ? Wq : (which == 1 ? Wk : Wv);
    v = W[(size_t)l * D_ * D_ + kk * D_ + n];
  } else if (r < WSEG_QKV + WSEG_O) {
    int i = r - WSEG_QKV;
    int n = i / D_, kk = i % D_;
    v = Wo[(size_t)l * D_ * D_ + kk * D_ + n];
  } else if (r < WSEG_QKV + WSEG_O + WSEG_1) {
    int i = r - WSEG_QKV - WSEG_O;
    int n = i / D_, kk = i % D_;
    v = W1[(size_t)l * D_ * DFF_ + kk * DFF_ + n];
  } else {
    int i = r - WSEG_QKV - WSEG_O - WSEG_1;
    int n = i / DFF_, kk = i % DFF_;
    v = W2[(size_t)l * DFF_ * D_ + kk * D_ + n];
  }
  out[idx] = f2bf(v);
}

// ---------------------------------------------------------------------------
// MFMA helper: wave tile = 16 rows x 32 cols (2 tiles of 16x16), K=128 in 4
// steps of 32. LDS: 16B chunks XOR-swizzled [row*128 + ((c^(row&15))<<3)].
// ---------------------------------------------------------------------------
__device__ __forceinline__ void mfma2(const unsigned short* As, const unsigned short* Bs,
                                      int w, int quad, int l16, f32x4 (&acc)[2]) {
#pragma unroll
  for (int kk = 0; kk < 4; ++kk) {
    int cb = kk * 4 + quad;
    int row = l16;
    bf16x8 a = __builtin_bit_cast(bf16x8, *(const uint4*)&As[row * 128 + ((cb ^ row) << 3)]);
    bf16x8 bb[2];
#pragma unroll
    for (int ct = 0; ct < 2; ++ct) {
      int n = w * 32 + ct * 16 + l16;
      bb[ct] = __builtin_bit_cast(bf16x8, *(const uint4*)&Bs[n * 128 + ((cb ^ (n & 15)) << 3)]);
    }
#pragma unroll
    for (int ct = 0; ct < 2; ++ct)
      acc[ct] = __builtin_amdgcn_mfma_f32_16x16x32_bf16(a, bb[ct], acc[ct], 0, 0, 0);
  }
}

// ---------------------------------------------------------------------------
// Fence-free grid barrier (R10-proven): kv is the only cross-block data and
// all kv traffic is agent-scope atomic (LLC-coherent, bypasses per-XCD L2).
// __syncthreads drains each wave's stores before the counter bump.
// Per-batch counters: only same-batch blocks (96) participate.
// ---------------------------------------------------------------------------
__device__ __forceinline__ void grid_barrier(unsigned* cnt, unsigned target) {
  __syncthreads();
  if (threadIdx.x == 0) {
    __hip_atomic_fetch_add(cnt, 1u, __ATOMIC_RELAXED, __HIP_MEMORY_SCOPE_AGENT);
    while (__hip_atomic_load(cnt, __ATOMIC_RELAXED, __HIP_MEMORY_SCOPE_AGENT) < target)
      __builtin_amdgcn_s_sleep(4);
  }
  __syncthreads();
}

// ---------------------------------------------------------------------------
// Persistent mega-kernel: all 6 layers + fc head.
// grid = 768 blocks x 256 thr (4 waves); block owns 16 rows; 3 blocks/CU so
// one block's staging/sync/barrier stalls hide under another's compute.
// Wave w: rows 0-15, cols [32w, 32w+32). x in registers; Q block-local (Cs);
// bf16 K/V cross blocks via agent atomics (dbuffered); per-batch barrier.
// LDS: As 4K + Bs 32K + Cs 8K + sKeys 2K + red 0.6K ~= 47 KB -> 3/CU.
// ---------------------------------------------------------------------------
__global__ void __launch_bounds__(256, 3) mega_kernel(
    const float* __restrict__ x0, unsigned short* __restrict__ kv0,
    unsigned short* __restrict__ kv1, const unsigned short* __restrict__ wbf,
    const float* __restrict__ g1, const float* __restrict__ b1,
    const float* __restrict__ g2, const float* __restrict__ b2,
    const int* __restrict__ tt, const float* __restrict__ table,
    const int* __restrict__ adj, const int* __restrict__ adjc,
    const float* __restrict__ fcw, const float* __restrict__ fcb,
    float* __restrict__ out, unsigned* barrier_cnt) {
  __shared__ unsigned short As[RPB * 128];       // 4 KB
  __shared__ unsigned short Bs[128 * 128];       // 32 KB
  __shared__ unsigned short Cs[2 * RPB * 128];   // 8 KB: [0:2048] Q/KV, [2048:] hf
  __shared__ float red1[4][RPB], red2[4][RPB];
  __shared__ int sKeys[RPB * LKEY];              // 2 KB
  __shared__ int sCnt[RPB];
  const int row0 = blockIdx.x * RPB;
  const int b = row0 / S_;
  const int bS = b * S_;
  const int t = threadIdx.x, w = t >> 6, lane = t & 63, quad = lane >> 4, l16 = lane & 15;
  const int tbase = tt[b] * D_;
  unsigned* bcnt = barrier_cnt + b * 32;  // per-batch counter, 128 B apart

  // persistent x in registers (MFMA C-layout): row=row0+quad*4+i, col=w*32+ct*16+l16
  f32x4 xreg[2];
#pragma unroll
  for (int ct = 0; ct < 2; ++ct)
#pragma unroll
    for (int i = 0; i < 4; ++i) {
      int row = row0 + quad * 4 + i;
      int col = w * 32 + ct * 16 + l16;
      xreg[ct][i] = x0[(size_t)row * D_ + col];
    }
  if (t < RPB) sCnt[t] = adjc[row0 + t - bS];
  for (int i = t; i < RPB * LKEY; i += 256) {
    int r = i / LKEY, j = i % LKEY;
    sKeys[i] = adj[(row0 + r - bS) * MAXDEG + j];  // tail values unused (clamped)
  }

  for (int l = 0; l < L_; ++l) {
    const unsigned short* wl = wbf + (size_t)l * WLAYER;
    const float* g1l = g1 + l * D_;
    const float* b1l = b1 + l * D_;
    const float* g2l = g2 + l * D_;
    const float* b2l = b2 + l * D_;
    unsigned short* kv = (l & 1) ? kv1 : kv0;

    // ---------------- LN1 on register x -> bf16 h in As --------------------
    float mu1[4], rs1[4];
#pragma unroll
    for (int i = 0; i < 4; ++i) {
      float s = xreg[0][i] + xreg[1][i];
      for (int off = 1; off < 16; off <<= 1) s += __shfl_xor(s, off);
      if (l16 == 0) red1[w][quad * 4 + i] = s;
    }
    __syncthreads();
#pragma unroll
    for (int i = 0; i < 4; ++i) {
      int r = quad * 4 + i;
      mu1[i] = (red1[0][r] + red1[1][r] + red1[2][r] + red1[3][r]) * (1.f / 128.f);
      float sq = 0.f;
#pragma unroll
      for (int ct = 0; ct < 2; ++ct) { float d = xreg[ct][i] - mu1[i]; sq += d * d; }
      for (int off = 1; off < 16; off <<= 1) sq += __shfl_xor(sq, off);
      if (l16 == 0) red2[w][r] = sq;
    }
    __syncthreads();
#pragma unroll
    for (int i = 0; i < 4; ++i) {
      int r = quad * 4 + i;
      rs1[i] = rsqrtf((red2[0][r] + red2[1][r] + red2[2][r] + red2[3][r]) * (1.f / 128.f) + 1e-5f);
    }
#pragma unroll
    for (int ct = 0; ct < 2; ++ct)
#pragma unroll
      for (int i = 0; i < 4; ++i) {
        int rowL = quad * 4 + i;
        int col = w * 32 + ct * 16 + l16;
        float h = (xreg[ct][i] - mu1[i]) * rs1[i] * g1l[col] + b1l[col];
        As[rowL * 128 + (((col >> 3) ^ rowL) << 3) + (col & 7)] = f2bf(h);
      }

    // ------- QKV GEMMs: K, V (via Cs -> atomic kv), then Q -> Cs -----------
    const int segs[3] = {1, 2, 0};
    for (int si = 0; si < 3; ++si) {
      const int seg = segs[si];
      for (int i = t; i < 2048; i += 256) {  // Bs <- seg's 128x128 tile
        int rr = i >> 4, cc = i & 15;
        uint4 vb = *(const uint4*)&wl[(size_t)(seg * 128 + rr) * 128 + cc * 8];
        *(uint4*)&Bs[rr * 128 + ((cc ^ (rr & 15)) << 3)] = vb;
      }
      __syncthreads();  // Bs staged; As/Cs hazards covered
      f32x4 acc[2];
      acc[0] = f32x4{0.f, 0.f, 0.f, 0.f};
      acc[1] = f32x4{0.f, 0.f, 0.f, 0.f};
      mfma2(As, Bs, w, quad, l16, acc);
      if (seg == 0) {  // Q -> Cs[0:2048] swizzled A-layout (kept for attention)
#pragma unroll
        for (int ct = 0; ct < 2; ++ct)
#pragma unroll
          for (int i = 0; i < 4; ++i) {
            int rowL = quad * 4 + i;
            int col = w * 32 + ct * 16 + l16;
            Cs[rowL * 128 + (((col >> 3) ^ rowL) << 3) + (col & 7)] = f2bf(acc[ct][i]);
          }
      } else {  // K or V: Cs linear -> coalesced agent-scope dword stores
#pragma unroll
        for (int ct = 0; ct < 2; ++ct)
#pragma unroll
          for (int i = 0; i < 4; ++i) {
            int rowL = quad * 4 + i;
            int col = w * 32 + ct * 16 + l16;
            Cs[rowL * 128 + col] = f2bf(acc[ct][i]);
          }
        __syncthreads();
        const int cbase = (seg == 1) ? 0 : 128;
        for (int i = t; i < RPB * 64; i += 256) {  // 1024 dwords
          int rL = i >> 6, cw = i & 63;
          unsigned u = *(const unsigned*)&Cs[rL * 128 + cw * 2];
          __hip_atomic_store((unsigned*)&kv[(size_t)(row0 + rL) * 256 + cbase + cw * 2],
                             u, __ATOMIC_RELAXED, __HIP_MEMORY_SCOPE_AGENT);
        }
      }
      __syncthreads();  // before next seg overwrites Bs/Cs
    }

    // -------- per-batch fence-free barrier: batch kv visible ---------------
    grid_barrier(bcnt, (unsigned)(BPBATCH * (l + 1)));

    // stage Bs <- Wo^T (flies under the attention gather)
    for (int i = t; i < 2048; i += 256) {
      int rr = i >> 4, cc = i & 15;
      uint4 vb = *(const uint4*)&wl[(size_t)(WSEG_QKV + rr * 128 + cc * 8)];
      *(uint4*)&Bs[rr * 128 + ((cc ^ (rr & 15)) << 3)] = vb;
    }

    // ---------------- attention (16 rows x 8 heads = 128 tasks) ------------
    if (t < RPB * 8) {
      const int rL = t >> 3, h = t & 7;
      const int s = row0 + rL - bS;
      const int cnt = sCnt[rL];
      float q[16];
      {
        u16x8 qa = *(const u16x8*)&Cs[rL * 128 + (((2 * h) ^ rL) << 3)];
        u16x8 qb = *(const u16x8*)&Cs[rL * 128 + (((2 * h + 1) ^ rL) << 3)];
#pragma unroll
        for (int j = 0; j < 8; ++j) { q[j] = bf2f(qa[j]); q[8 + j] = bf2f(qb[j]); }
      }
      float m = -1e30f, lsum = 0.f;
      float o16[16];
#pragma unroll
      for (int j = 0; j < 16; ++j) o16[j] = 0.f;
      for (int jb = 0; jb < cnt; jb += 4) {  // 4 neighbors in flight
        unsigned long long K[4][4], V[4][4];
#pragma unroll
        for (int u = 0; u < 4; ++u) {
          int j = jb + u;
          int key = 0;
          if (j < cnt) key = (j < LKEY) ? sKeys[rL * LKEY + j] : adj[s * MAXDEG + j];
          const unsigned long long* kp =
              (const unsigned long long*)(kv + (size_t)(bS + key) * 256 + h * 16);
#pragma unroll
          for (int c = 0; c < 4; ++c) {
            K[u][c] = __hip_atomic_load(kp + c, __ATOMIC_RELAXED, __HIP_MEMORY_SCOPE_AGENT);
            V[u][c] = __hip_atomic_load(kp + 32 + c, __ATOMIC_RELAXED, __HIP_MEMORY_SCOPE_AGENT);
          }
        }
#pragma unroll
        for (int u = 0; u < 4; ++u) {
          float kf[16], vf[16];
#pragma unroll
          for (int c = 0; c < 4; ++c) { ull2f4(K[u][c], kf + 4 * c); ull2f4(V[u][c], vf + 4 * c); }
          float dot = 0.f;
#pragma unroll
          for (int j = 0; j < 16; ++j) dot = fmaf(q[j], kf[j], dot);
          dot *= 0.25f;  // 1/sqrt(HD)
          if (jb + u >= cnt) dot = -1e30f;
          const float mn = fmaxf(m, dot);
          const float rescale = __expf(m - mn);
          const float e = __expf(dot - mn);
          lsum = lsum * rescale + e;
#pragma unroll
          for (int j = 0; j < 16; ++j) o16[j] = o16[j] * rescale + e * vf[j];
          m = mn;
        }
      }
      const float inv = 1.f / lsum;
      u16x8 pk0, pk1;
#pragma unroll
      for (int j = 0; j < 8; ++j) {
        pk0[j] = f2bf(o16[j] * inv);
        pk1[j] = f2bf(o16[8 + j] * inv);
      }
      *(u16x8*)&As[rL * 128 + (((2 * h) ^ rL) << 3)] = pk0;
      *(u16x8*)&As[rL * 128 + (((2 * h + 1) ^ rL) << 3)] = pk1;
    }
    __syncthreads();  // As(o) + Bs(Wo) ready

    // ---------------- x' = x + o@Wo; LN2*te; FFN; residual -----------------
    f32x4 acc1[2];
    acc1[0] = f32x4{0.f, 0.f, 0.f, 0.f};
    acc1[1] = f32x4{0.f, 0.f, 0.f, 0.f};
    mfma2(As, Bs, w, quad, l16, acc1);
    f32x4 xp[2];
#pragma unroll
    for (int ct = 0; ct < 2; ++ct)
#pragma unroll
      for (int i = 0; i < 4; ++i) xp[ct][i] = xreg[ct][i] + acc1[ct][i];
#pragma unroll
    for (int i = 0; i < 4; ++i) {
      float s = xp[0][i] + xp[1][i];
      for (int off = 1; off < 16; off <<= 1) s += __shfl_xor(s, off);
      if (l16 == 0) red1[w][quad * 4 + i] = s;
    }
    __syncthreads();
    float mu_[4], rs_[4];
#pragma unroll
    for (int i = 0; i < 4; ++i) {
      int r = quad * 4 + i;
      mu_[i] = (red1[0][r] + red1[1][r] + red1[2][r] + red1[3][r]) * (1.f / 128.f);
      float sq = 0.f;
#pragma unroll
      for (int ct = 0; ct < 2; ++ct) { float d = xp[ct][i] - mu_[i]; sq += d * d; }
      for (int off = 1; off < 16; off <<= 1) sq += __shfl_xor(sq, off);
      if (l16 == 0) red2[w][r] = sq;
    }
    __syncthreads();
#pragma unroll
    for (int i = 0; i < 4; ++i) {
      int r = quad * 4 + i;
      rs_[i] = rsqrtf((red2[0][r] + red2[1][r] + red2[2][r] + red2[3][r]) * (1.f / 128.f) + 1e-5f);
    }
#pragma unroll
    for (int ct = 0; ct < 2; ++ct)
#pragma unroll
      for (int i = 0; i < 4; ++i) {
        int rowL = quad * 4 + i;
        int col = w * 32 + ct * 16 + l16;
        float h2 = (xp[ct][i] - mu_[i]) * rs_[i] * g2l[col] + b2l[col];
        h2 *= table[tbase + col];
        As[rowL * 128 + (((col >> 3) ^ rowL) << 3) + (col & 7)] = f2bf(h2);
      }
    f32x4 acc2[2];
    acc2[0] = f32x4{0.f, 0.f, 0.f, 0.f};
    acc2[1] = f32x4{0.f, 0.f, 0.f, 0.f};
    const unsigned short* w1 = wl + WSEG_QKV + WSEG_O;
    const unsigned short* w2 = wl + WSEG_QKV + WSEG_O + WSEG_1;
    unsigned short* hf = Cs + RPB * 128;  // [2048:4096]
    for (int c = 0; c < 4; ++c) {
      __syncthreads();  // h2/As visible (c==0); prior W2 mfma done with Bs (c>0)
      for (int i = t; i < 2048; i += 256) {
        int rr = i >> 4, cc = i & 15;
        uint4 vb = *(const uint4*)&w1[(size_t)(c * 128 + rr) * 128 + cc * 8];
        *(uint4*)&Bs[rr * 128 + ((cc ^ (rr & 15)) << 3)] = vb;
      }
      __syncthreads();
      f32x4 accF[2];
      accF[0] = f32x4{0.f, 0.f, 0.f, 0.f};
      accF[1] = f32x4{0.f, 0.f, 0.f, 0.f};
      mfma2(As, Bs, w, quad, l16, accF);
#pragma unroll
      for (int ct = 0; ct < 2; ++ct)
#pragma unroll
        for (int i = 0; i < 4; ++i) {
          int rowL = quad * 4 + i;
          int col = w * 32 + ct * 16 + l16;
          hf[rowL * 128 + (((col >> 3) ^ rowL) << 3) + (col & 7)] =
              f2bf(fmaxf(accF[ct][i], 0.f));
        }
      __syncthreads();  // hf visible; Bs(W1c) reads done
      for (int i = t; i < 2048; i += 256) {
        int rr = i >> 4, cc = i & 15;
        uint4 vb = *(const uint4*)&w2[(size_t)rr * 512 + c * 128 + cc * 8];
        *(uint4*)&Bs[rr * 128 + ((cc ^ (rr & 15)) << 3)] = vb;
      }
      __syncthreads();
      mfma2(hf, Bs, w, quad, l16, acc2);
    }
    // epilogue: x'' = x' + ffn (registers only)
    if (l < L_ - 1) {
#pragma unroll
      for (int ct = 0; ct < 2; ++ct)
#pragma unroll
        for (int i = 0; i < 4; ++i) xreg[ct][i] = xp[ct][i] + acc2[ct][i];
      __syncthreads();  // last FFN mfma done reading hf/Bs before next layer
    } else {
      float pr[4] = {0.f, 0.f, 0.f, 0.f};
#pragma unroll
      for (int ct = 0; ct < 2; ++ct)
#pragma unroll
        for (int i = 0; i < 4; ++i)
          pr[i] += (xp[ct][i] + acc2[ct][i]) * fcw[w * 32 + ct * 16 + l16];
#pragma unroll
      for (int i = 0; i < 4; ++i) {
        float s = pr[i];
        for (int off = 1; off < 16; off <<= 1) s += __shfl_xor(s, off);
        if (l16 == 0) red1[w][quad * 4 + i] = s;
      }
      __syncthreads();
      if (w == 0 && l16 == 0)
#pragma unroll
        for (int i = 0; i < 4; ++i) {
          int r = quad * 4 + i;
          out[row0 + r] = red1[0][r] + red1[1][r] + red1[2][r] + red1[3][r] + fcb[0];
        }
    }
  }
}

// ---------------------------------------------------------------------------
extern "C" void kernel_launch(void* const* d_in, const int* in_sizes, int n_in,
                              void* d_out, int out_size, void* d_ws, size_t ws_size,
                              hipStream_t stream) {
  const float* r_t       = (const float*)d_in[0];
  const int*   t         = (const int*)d_in[1];
  const int*   pcm       = (const int*)d_in[2];
  const float* src_embed = (const float*)d_in[4];
  const float* time_tab  = (const float*)d_in[5];
  const float* Wq = (const float*)d_in[6];
  const float* Wk = (const float*)d_in[7];
  const float* Wv = (const float*)d_in[8];
  const float* Wo = (const float*)d_in[9];
  const float* W1 = (const float*)d_in[10];
  const float* W2 = (const float*)d_in[11];
  const float* g1 = (const float*)d_in[12];
  const float* b1 = (const float*)d_in[13];
  const float* g2 = (const float*)d_in[14];
  const float* b2 = (const float*)d_in[15];
  const float* fc_w = (const float*)d_in[16];
  const float* fc_b = (const float*)d_in[17];
  float* out = (float*)d_out;

  char* ws = (char*)d_ws;
  size_t off = 0;
  auto alloc = [&](size_t bytes) -> void* {
    void* p = ws + off;
    off = (off + bytes + 255) & ~(size_t)255;
    return p;
  };
  float*          x    = (float*)alloc((size_t)ROWS * D_ * 4);
  unsigned short* kv0  = (unsigned short*)alloc((size_t)ROWS * 256 * 2);
  unsigned short* kv1  = (unsigned short*)alloc((size_t)ROWS * 256 * 2);
  int*            adj  = (int*)alloc((size_t)S_ * MAXDEG * 4);
  int*            adjc = (int*)alloc((size_t)S_ * 4);
  unsigned short* wbf  = (unsigned short*)alloc((size_t)L_ * WLAYER * 2);
  unsigned*       bcnt = (unsigned*)alloc(8 * 32 * 4);

  adj_kernel<<<S_, 64, 0, stream>>>(pcm, adj, adjc);
  wconv_kernel<<<(L_ * WLAYER + 255) / 256, 256, 0, stream>>>(Wq, Wk, Wv, Wo, W1, W2, wbf);
  xinit_kernel<<<ROWS, 128, 0, stream>>>(r_t, adj, adjc, src_embed, t, time_tab, x, bcnt);

  mega_kernel<<<NBLK, 256, 0, stream>>>(x, kv0, kv1, wbf, g1, b1, g2, b2,
                                        t, time_tab, adj, adjc, fc_w, fc_b, out, bcnt);
}